// Round 2
// baseline (133.136 us; speedup 1.0000x reference)
//
#include <hip/hip_runtime.h>
#include <hip/hip_bf16.h>
#include <math.h>

#define NB 4096    // batch
#define NN 8192    // N = B * n_views
#define DD 128     // feature dim
#define NCLS 100   // label values 0..99
#define NSPLIT 32  // j-splits in k_main

constexpr float INV_T = 14.285714285714286f;      // 1/0.07 (also the subtracted row max)
constexpr float EC1   = 20.609929155556620f;      // INV_T * log2(e)
constexpr float EC0   = -20.609929155556620f;     // -INV_T * log2(e)
constexpr float LN2   = 0.6931471805599453f;

typedef __attribute__((ext_vector_type(8))) short bf16x8;
typedef __attribute__((ext_vector_type(4))) float f32x4;

__device__ __forceinline__ float bf2f(ushort u) {
    union { unsigned int i; float f; } v; v.i = ((unsigned int)u) << 16; return v.f;
}

// ---------------- kernel 1: L2-normalize rows -> bf16; also zero S/counts ----------------
__global__ __launch_bounds__(256) void k_normalize(const float* __restrict__ feat,
                                                   __hip_bfloat16* __restrict__ fb,
                                                   float* __restrict__ zero_region) {
    // zero S (100*128 floats) + counts (100 ints) = 12900 dwords; stream order
    // guarantees completion before k_classsum.
    if (blockIdx.x < 51) {
        int idx = blockIdx.x * 256 + threadIdx.x;
        if (idx < NCLS * DD + NCLS) zero_region[idx] = 0.0f;
    }
    int wave = (blockIdx.x * 256 + threadIdx.x) >> 6;   // one wave per row
    int lane = threadIdx.x & 63;
    const float2 v = ((const float2*)(feat + (size_t)wave * DD))[lane];
    float ss = v.x * v.x + v.y * v.y;
#pragma unroll
    for (int off = 1; off < 64; off <<= 1) ss += __shfl_xor(ss, off, 64);
    float scale = 1.0f / fmaxf(sqrtf(ss), 1e-12f);
    __hip_bfloat162 h2;
    h2.x = __float2bfloat16(v.x * scale);
    h2.y = __float2bfloat16(v.y * scale);
    ((__hip_bfloat162*)(fb + (size_t)wave * DD))[lane] = h2;
}

// ---------------- kernel 2: per-class feature sums S_c + class counts ----------------
// grid 800: c = bid>>3 (class), chunk = bid&7 (512 batch entries each).
__global__ __launch_bounds__(256) void k_classsum(const ushort* __restrict__ fb,
                                                  const int* __restrict__ labels,
                                                  float* __restrict__ S,
                                                  int* __restrict__ counts) {
    const int c     = blockIdx.x >> 3;
    const int chunk = blockIdx.x & 7;
    const int view  = threadIdx.x >> 7;      // 0 or 1
    const int d     = threadIdx.x & 127;
    float s = 0.0f;
    int nmatch = 0;
    const int b0 = chunk * 512;
    for (int b = b0; b < b0 + 512; ++b) {
        if (labels[b] == c) {                 // uniform branch, scalar load
            s += bf2f(fb[(size_t)(b + view * NB) * DD + d]);
            ++nmatch;
        }
    }
    atomicAdd(&S[c * DD + d], s);
    if (threadIdx.x == 0) atomicAdd(&counts[c], nmatch);
}

// ---------------- kernel 3: F*F^T with fused row-sum of exp ----------------
// Wave job: 64 rows (4 tiles of 16) x 256-column j-range (16 j-tiles).
// Waves in a block share the j-range (B frags hit L1), differ in row group.
// Epilogue per element: fma + v_exp_f32 + add. No masks, no labels, no self check.
__global__ __launch_bounds__(256) void k_main(const ushort* __restrict__ fb,
                                              float* __restrict__ g_se2) {
    const int lane = threadIdx.x & 63;
    const int w    = threadIdx.x >> 6;
    const int js   = blockIdx.x & 31;                 // j-split 0..31
    const int rg   = (blockIdx.x >> 5) * 4 + w;       // row group 0..127
    const int i0   = rg * 64;
    const int q    = lane >> 4;
    const int n15  = lane & 15;

    // A fragments: 4 row-tiles x 4 k-tiles, resident whole kernel (64 VGPRs)
    bf16x8 afrag[4][4];
#pragma unroll
    for (int tt = 0; tt < 4; ++tt) {
        const ushort* rp = fb + (size_t)(i0 + tt * 16 + n15) * DD + q * 8;
#pragma unroll
        for (int kt = 0; kt < 4; ++kt)
            afrag[tt][kt] = *(const bf16x8*)(rp + kt * 32);
    }

    float a_se[16] = {};
    const ushort* bp = fb + (size_t)(js * 256 + n15) * DD + q * 8;

#pragma unroll 2
    for (int it = 0; it < 16; ++it) {
        bf16x8 bf[4];
#pragma unroll
        for (int kt = 0; kt < 4; ++kt) bf[kt] = *(const bf16x8*)(bp + kt * 32);
        bp += 16 * DD;
#pragma unroll
        for (int tt = 0; tt < 4; ++tt) {
            f32x4 a = {0.f, 0.f, 0.f, 0.f};
#pragma unroll
            for (int kt = 0; kt < 4; ++kt)
                a = __builtin_amdgcn_mfma_f32_16x16x32_bf16(afrag[tt][kt], bf[kt], a, 0, 0, 0);
#pragma unroll
            for (int r = 0; r < 4; ++r)
                a_se[tt * 4 + r] += __builtin_amdgcn_exp2f(fmaf(a[r], EC1, EC0));
        }
    }

    // lanes n15=0..15 within a quad hold the same rows; reduce, then plain store
    // (each (js,row) slot written by exactly one wave -> no atomics, no memset)
#pragma unroll
    for (int s = 0; s < 16; ++s) {
        float v = a_se[s];
#pragma unroll
        for (int off = 1; off < 16; off <<= 1) v += __shfl_xor(v, off, 64);
        if (n15 == 0)
            g_se2[js * NN + i0 + (s >> 2) * 16 + q * 4 + (s & 3)] = v;
    }
}

// ---------------- kernel 4: per-row loss -> per-block partial ----------------
__global__ __launch_bounds__(256) void k_final(const ushort* __restrict__ fb,
                                               const int* __restrict__ labels,
                                               const float* __restrict__ g_se2,
                                               const float* __restrict__ S,
                                               const int* __restrict__ counts,
                                               float* __restrict__ partial) {
    const int r = blockIdx.x * 256 + threadIdx.x;
    const int c = labels[r & (NB - 1)];
    const ushort* fp = fb + (size_t)r * DD;
    const float*  sp = S + c * DD;
    float s1 = 0.0f, s2 = 0.0f;   // dot(f_i, S_c), dot(f_i, f_i) in fp32 from bf16 row
#pragma unroll
    for (int k = 0; k < DD; k += 4) {
        ushort4 u = *(const ushort4*)(fp + k);
        float4 sv = *(const float4*)(sp + k);
        float x0 = bf2f(u.x), x1 = bf2f(u.y), x2 = bf2f(u.z), x3 = bf2f(u.w);
        s1 = fmaf(x0, sv.x, fmaf(x1, sv.y, fmaf(x2, sv.z, fmaf(x3, sv.w, s1))));
        s2 = fmaf(x0, x0, fmaf(x1, x1, fmaf(x2, x2, fmaf(x3, x3, s2))));
    }
    float sum32 = 0.0f;
#pragma unroll
    for (int t = 0; t < NSPLIT; ++t) sum32 += g_se2[t * NN + r];

    float selfexp = __builtin_amdgcn_exp2f(fmaf(s2, EC1, EC0));  // same fn as epilogue's self term
    float se   = sum32 - selfexp;                                 // sum_{j!=i} exp(l_ij)
    float cnt  = (float)(2 * counts[c] - 1);
    float possum = INV_T * (s1 - s2) - cnt * INV_T;
    float lg   = __builtin_amdgcn_logf(se + 1e-12f) * LN2;
    float mlpp = (possum - cnt * lg) / fmaxf(cnt, 1.0f);
    float v = -mlpp * (1.0f / (float)NN);

#pragma unroll
    for (int off = 1; off < 64; off <<= 1) v += __shfl_xor(v, off, 64);
    __shared__ float sred[4];
    if ((threadIdx.x & 63) == 0) sred[threadIdx.x >> 6] = v;
    __syncthreads();
    if (threadIdx.x == 0) partial[blockIdx.x] = sred[0] + sred[1] + sred[2] + sred[3];
}

// ---------------- kernel 5: sum 32 partials -> out ----------------
__global__ void k_sum(const float* __restrict__ partial, float* __restrict__ out) {
    float v = (threadIdx.x < 32) ? partial[threadIdx.x] : 0.0f;
#pragma unroll
    for (int off = 1; off < 32; off <<= 1) v += __shfl_xor(v, off, 64);
    if (threadIdx.x == 0) out[0] = v;
}

extern "C" void kernel_launch(void* const* d_in, const int* in_sizes, int n_in,
                              void* d_out, int out_size, void* d_ws, size_t ws_size,
                              hipStream_t stream) {
    const float* feat  = (const float*)d_in[0];
    const int* labels  = (const int*)d_in[1];
    float* out         = (float*)d_out;
    char* ws           = (char*)d_ws;

    __hip_bfloat16* fb = (__hip_bfloat16*)ws;                        // 2 MB
    float* g_se2 = (float*)(ws + (size_t)2 * 1024 * 1024);           // 1 MB [NSPLIT][NN]
    float* S     = (float*)(ws + (size_t)3 * 1024 * 1024);           // 100*128 f32
    int*   counts= (int*)(S + NCLS * DD);                            // 100 i32 (contiguous after S)
    float* partial = (float*)(ws + (size_t)3 * 1024 * 1024 + 64 * 1024); // 32 f32

    k_normalize<<<NN / 4, 256, 0, stream>>>(feat, fb, S);
    k_classsum<<<NCLS * 8, 256, 0, stream>>>((const ushort*)fb, labels, S, counts);
    k_main<<<(NN / 64 / 4) * NSPLIT, 256, 0, stream>>>((const ushort*)fb, g_se2);
    k_final<<<NN / 256, 256, 0, stream>>>((const ushort*)fb, labels, g_se2, S, counts, partial);
    k_sum<<<1, 64, 0, stream>>>(partial, out);
}